// Round 7
// baseline (655.821 us; speedup 1.0000x reference)
//
#include <hip/hip_runtime.h>
#include <hip/hip_bf16.h>

typedef __attribute__((ext_vector_type(8))) short short8;
typedef __attribute__((ext_vector_type(8))) unsigned short ushort8;
typedef __attribute__((ext_vector_type(4))) float f32x4;
typedef __attribute__((ext_vector_type(2))) unsigned int uint2v;
typedef __attribute__((ext_vector_type(4))) unsigned int uint4v;

#define DN   128
#define DE   64
#define DIN  192
#define HID  256
#define OUTD 128
#define TE   64      // edges per block
#define NT   256     // threads per block (4 waves)
#define MSG_LD 200   // msg bf16 row stride (192 + 8 pad)
#define OUT_LD 132   // f32 out tile stride; 64*132*4 = 33792 = LDS union size
#define NMB  (TE / 16)

static __device__ __forceinline__ unsigned short f2b(float f) {
    unsigned int u = __float_as_uint(f);
    u += 0x7fffu + ((u >> 16) & 1u);
    return (unsigned short)(u >> 16);
}

// packed RNE f32x2 -> bf16x2 (gfx950 native)
static __device__ __forceinline__ unsigned int cvt_pk2(float lo, float hi) {
    unsigned int r;
    asm("v_cvt_pk_bf16_f32 %0, %1, %2" : "=v"(r) : "v"(lo), "v"(hi));
    return r;
}

// hardware transpose-read: per-lane addr selects an 8B slot in a 128B-aligned
// 4x16 bf16 row-major region; lane receives column (addr%128)/8 (elems col+j*16).
template<int OFF>
static __device__ __forceinline__ uint2v tr_read(unsigned addr) {
    uint2v d;
    asm volatile("ds_read_b64_tr_b16 %0, %1 offset:%c2"
                 : "=v"(d) : "v"(addr), "n"(OFF));
    return d;
}

// Fused prep: (a) pack 4 weight mats to bf16 fragment layout Wp[((k/32)*Nc+n)*32+(k%32)]
//     (coalesced WRITES, scattered reads -> L2 absorbs reads),
// (b) histogram dest rows per branch, (c) convert x to bf16.
__global__ __launch_bounds__(256)
void prep_kernel(const float* __restrict__ W1o, const float* __restrict__ W1i,
                 const float* __restrict__ W2o, const float* __restrict__ W2i,
                 unsigned short* __restrict__ W1po, unsigned short* __restrict__ W1pi,
                 unsigned short* __restrict__ W2po, unsigned short* __restrict__ W2pi,
                 const int* __restrict__ ei, int E, int N, int* __restrict__ hist,
                 const float* __restrict__ x, unsigned short* __restrict__ xb) {
    const int S1 = DIN * HID, S2v = HID * OUTD;
    const int PACKN = 2 * S1 + 2 * S2v;
    int idx = blockIdx.x * blockDim.x + threadIdx.x;
    if (idx < PACKN) {
        // j = PACKED index (linear per thread -> coalesced 2B stores).
        if (idx < 2 * S1) {
            const float* W = (idx < S1) ? W1o : W1i;
            unsigned short* Wp = (idx < S1) ? W1po : W1pi;
            int j = (idx < S1) ? idx : idx - S1;
            int k5 = j & 31, t = j >> 5;
            int n = t & (HID - 1), kq = t >> 8;
            Wp[j] = f2b(W[(kq * 32 + k5) * HID + n]);
        } else {
            const float* W = (idx < 2 * S1 + S2v) ? W2o : W2i;
            unsigned short* Wp = (idx < 2 * S1 + S2v) ? W2po : W2pi;
            int j = (idx < 2 * S1 + S2v) ? idx - 2 * S1 : idx - 2 * S1 - S2v;
            int k5 = j & 31, t = j >> 5;
            int n = t & (OUTD - 1), kq = t >> 7;
            Wp[j] = f2b(W[(kq * 32 + k5) * OUTD + n]);
        }
    } else if (idx < PACKN + E) {
        int e = idx - PACKN;
        int r = ei[e], c = ei[E + e];
        if      (r < c) atomicAdd(&hist[r], 1);
        else if (r > c) atomicAdd(&hist[N + r], 1);
    } else {
        int i = idx - PACKN - E;           // 8 x-floats per thread
        if (i < N * DN / 8) {
            float4 a = reinterpret_cast<const float4*>(x)[i * 2];
            float4 b = reinterpret_cast<const float4*>(x)[i * 2 + 1];
            ushort8 v = { f2b(a.x), f2b(a.y), f2b(a.z), f2b(a.w),
                          f2b(b.x), f2b(b.y), f2b(b.z), f2b(b.w) };
            reinterpret_cast<ushort8*>(xb)[i] = v;
        }
    }
}

// Per-chunk (1024 rows) exclusive scan of one branch's histogram.
__global__ __launch_bounds__(1024)
void scan1_kernel(const int* __restrict__ hist, int* __restrict__ cursor,
                  int* __restrict__ chunkSum, int N, int nch) {
    __shared__ int s_ws[16];
    const int br = blockIdx.x / nch, ch = blockIdx.x - br * nch;
    const int tid = threadIdx.x, lane = tid & 63, wv = tid >> 6;
    const int i = ch * 1024 + tid;
    int v = (i < N) ? hist[(size_t)br * N + i] : 0;
    int incl = v;
    #pragma unroll
    for (int d = 1; d < 64; d <<= 1) {
        int t = __shfl_up(incl, d, 64);
        if (lane >= d) incl += t;
    }
    if (lane == 63) s_ws[wv] = incl;
    __syncthreads();
    if (tid < 16) {
        int w = s_ws[tid];
        int wi = w;
        #pragma unroll
        for (int d = 1; d < 16; d <<= 1) {
            int t = __shfl_up(wi, d, 64);
            if (tid >= d) wi += t;
        }
        s_ws[tid] = wi - w;
    }
    __syncthreads();
    int excl = s_ws[wv] + incl - v;
    if (i < N) cursor[(size_t)br * N + i] = excl;
    if (tid == 1023) chunkSum[br * nch + ch] = excl + v;
}

// Scan chunk sums (nch <= 64 per branch): wave 0 -> branch 0, wave 1 -> branch 1.
__global__ __launch_bounds__(128)
void scan2_kernel(int* __restrict__ chunkSum, int* __restrict__ cnt, int nch) {
    const int br = threadIdx.x >> 6, lane = threadIdx.x & 63;
    int v = (lane < nch) ? chunkSum[br * nch + lane] : 0;
    int incl = v;
    #pragma unroll
    for (int d = 1; d < 64; d <<= 1) {
        int t = __shfl_up(incl, d, 64);
        if (lane >= d) incl += t;
    }
    if (lane < nch) chunkSum[br * nch + lane] = incl - v;
    if (lane == nch - 1) cnt[br] = incl;
}

// Scatter edges to sorted-by-dest-row positions.
__global__ __launch_bounds__(256)
void reorder_kernel(const int* __restrict__ ei, int E, int N, int nch,
                    int* __restrict__ cursor, const int* __restrict__ chunkSum,
                    int* __restrict__ list_out, int* __restrict__ list_in) {
    int e = blockIdx.x * blockDim.x + threadIdx.x;
    if (e >= E) return;
    int r = ei[e], c = ei[E + e];
    if (r == c) return;
    int br = (r < c) ? 0 : 1;
    int p = chunkSum[br * nch + (r >> 10)] + atomicAdd(&cursor[(size_t)br * N + r], 1);
    (br ? list_in : list_out)[p] = e;
}

__global__ __launch_bounds__(NT, 4)
void mlp_scatter_kernel(const unsigned short* __restrict__ xb,
                        const int* __restrict__ ei,
                        const float* __restrict__ ea,
                        const unsigned short* __restrict__ W1p_out,
                        const unsigned short* __restrict__ W1p_in,
                        const float* __restrict__ b1_out,
                        const float* __restrict__ b1_in,
                        const unsigned short* __restrict__ W2p_out,
                        const unsigned short* __restrict__ W2p_in,
                        const float* __restrict__ b2_out,
                        const float* __restrict__ b2_in,
                        const int* __restrict__ list_out,
                        const int* __restrict__ list_in,
                        const int* __restrict__ cnt,
                        float* __restrict__ out,
                        int E) {
    // s_buf union (33792 B): msg bf16 [64][MSG_LD] (25600B) -> hT blocked bf16
    //                        (32768B) -> out f32 [64][OUT_LD].
    __shared__ __align__(16) unsigned short s_buf[TE * 264];
    __shared__ int s_eid[TE], s_dest[TE], s_col[TE];

    // Device-side branch mapping: no empty half-grid.
    const int c0 = cnt[0], c1 = cnt[1];
    const int nb0 = (c0 + TE - 1) / TE;
    const int branch = (blockIdx.x >= nb0) ? 1 : 0;   // 0 = out-flow, 1 = in-flow
    const int lb = branch ? (blockIdx.x - nb0) : blockIdx.x;
    const int count = branch ? c1 : c0;
    if (lb * TE >= count) return;
    const int* list            = branch ? list_in : list_out;
    const unsigned short* W1p  = branch ? W1p_in  : W1p_out;
    const float* b1            = branch ? b1_in   : b1_out;
    const unsigned short* W2p  = branch ? W2p_in  : W2p_out;
    const float* b2            = branch ? b2_in   : b2_out;
    const int colbase          = branch ? 0 : OUTD;  // out = concat(flow_in, flow_out)

    const int tid = threadIdx.x;
    if (tid < TE) {
        int idx = lb * TE + tid;
        int e = (idx < count) ? list[idx] : -1;
        s_eid[tid]  = e;
        s_dest[tid] = (e >= 0) ? ei[e] : -1;       // sorted non-decreasing dest rows
        s_col[tid]  = (e >= 0) ? ei[E + e] : 0;
    }
    __syncthreads();

    // Gather msg = concat(xb[col] (bf16), cvt(edge_attr[e])) into LDS. 4 threads/edge.
    {
        const int le  = tid >> 2;
        const int sub = tid & 3;
        const int e   = s_eid[le];
        const ushort8* xrow = reinterpret_cast<const ushort8*>(xb) + (size_t)s_col[le] * (DN / 8);
        #pragma unroll
        for (int j = 0; j < 4; ++j) {
            int seg = sub + j * 4;                       // elems [seg*8, seg*8+8)
            ushort8 v = {0, 0, 0, 0, 0, 0, 0, 0};
            if (e >= 0) v = xrow[seg];
            *reinterpret_cast<ushort8*>(&s_buf[le * MSG_LD + seg * 8]) = v;
        }
        const float4* erow = reinterpret_cast<const float4*>(ea) + (size_t)e * (DE / 4);
        #pragma unroll
        for (int jj = 0; jj < 2; ++jj) {
            float4 v0 = make_float4(0.f, 0.f, 0.f, 0.f), v1 = v0;
            if (e >= 0) { v0 = erow[sub * 4 + jj * 2]; v1 = erow[sub * 4 + jj * 2 + 1]; }
            uint4v w = { cvt_pk2(v0.x, v0.y), cvt_pk2(v0.z, v0.w),
                         cvt_pk2(v1.x, v1.y), cvt_pk2(v1.z, v1.w) };
            *reinterpret_cast<uint4v*>(&s_buf[le * MSG_LD + DN + sub * 16 + jj * 8]) = w;
        }
    }
    __syncthreads();

    const int wave = tid >> 6;     // 0..3
    const int lane = tid & 63;
    const int ln   = lane & 15;
    const int quad = lane >> 4;

    // ---- GEMM1: h = relu(msg @ W1 + b1).  M=64 (4 m-frags), N=256 (64/wave), K=192.
    f32x4 acc[4][4];
    {
        const int nbase = wave * 64;
        float bias[4];
        #pragma unroll
        for (int t = 0; t < 4; ++t) bias[t] = b1[nbase + t * 16 + ln];
        #pragma unroll
        for (int mt = 0; mt < 4; ++mt)
            #pragma unroll
            for (int t = 0; t < 4; ++t)
                acc[mt][t] = (f32x4){bias[t], bias[t], bias[t], bias[t]};
        #pragma unroll
        for (int kt = 0; kt < DIN / 32; ++kt) {
            short8 a[4], b[4];
            #pragma unroll
            for (int mt = 0; mt < 4; ++mt)
                a[mt] = *reinterpret_cast<const short8*>(
                    &s_buf[(mt * 16 + ln) * MSG_LD + kt * 32 + quad * 8]);
            #pragma unroll
            for (int t = 0; t < 4; ++t)
                b[t] = *reinterpret_cast<const short8*>(
                    &W1p[((kt * HID + nbase + t * 16 + ln) << 5) + quad * 8]);
            #pragma unroll
            for (int mt = 0; mt < 4; ++mt)
                #pragma unroll
                for (int t = 0; t < 4; ++t)
                    acc[mt][t] = __builtin_amdgcn_mfma_f32_16x16x32_bf16(a[mt], b[t], acc[mt][t], 0, 0, 0);
        }
    }
    __syncthreads();   // msg reads done; s_buf re-used for blocked-transposed h

    // ReLU -> bf16 hT blocked: tile (nq=n/4, mb=m/16) holds 4x16 row-major bf16 at
    // elem ((nq*NMB + mb)*64 + (n&3)*16 + (m&15)). One cvt_pk pair + one b64 write.
    {
        const int nbase = wave * 64;
        #pragma unroll
        for (int mt = 0; mt < 4; ++mt)
            #pragma unroll
            for (int t = 0; t < 4; ++t) {
                int n = nbase + t * 16 + ln;
                float r0 = acc[mt][t][0], r1 = acc[mt][t][1];
                float r2 = acc[mt][t][2], r3 = acc[mt][t][3];
                r0 = r0 > 0.f ? r0 : 0.f;  r1 = r1 > 0.f ? r1 : 0.f;
                r2 = r2 > 0.f ? r2 : 0.f;  r3 = r3 > 0.f ? r3 : 0.f;
                unsigned int d0 = cvt_pk2(r0, r1);
                unsigned int d1 = cvt_pk2(r2, r3);
                int el = (((n >> 2) * NMB + mt) << 6) + ((n & 3) << 4) + (quad << 2);
                *reinterpret_cast<uint2v*>(&s_buf[el]) = (uint2v){d0, d1};
            }
    }
    __syncthreads();

    // ---- GEMM2: o = h @ W2 + b2.  M-SPLIT across waves: wave w owns rows
    // [w*16, w*16+16) x ALL 128 cols.  Per kt: only 2 tr_reads (vs 8 with the
    // old N-split -> 4x less LDS tr traffic); 8 W2p B-frags come from L2 (hot).
    // Counted lgkmcnt(2) pipeline: issue kt+1's tr pair before waiting on kt's.
    f32x4 acc2[8];
    {
        #pragma unroll
        for (int t = 0; t < 8; ++t) {
            float bz = b2[t * 16 + ln];
            acc2[t] = (f32x4){bz, bz, bz, bz};
        }
        // A-frag region for (kt, wave): byte kt*4096 + quad*1024 + wave*128 (+512),
        // per-lane column slot ln*8.
        const unsigned trb = (unsigned)(uintptr_t)(&s_buf[quad * 512 + wave * 64 + ln * 4]);

#define G2ISSUE(kt) \
        uint2v t0_##kt = tr_read<(kt) * 4096>(trb); \
        uint2v t1_##kt = tr_read<(kt) * 4096 + 512>(trb);

#define G2BODY(kt, WAITN) { \
        short8 b[8]; \
        _Pragma("unroll") \
        for (int t = 0; t < 8; ++t) \
            b[t] = *reinterpret_cast<const short8*>( \
                &W2p[(((kt) * OUTD + t * 16 + ln) << 5) + quad * 8]); \
        asm volatile("s_waitcnt lgkmcnt(" #WAITN ")"); \
        __builtin_amdgcn_sched_barrier(0); \
        short8 a = __builtin_bit_cast(short8, \
            (uint4v){t0_##kt.x, t0_##kt.y, t1_##kt.x, t1_##kt.y}); \
        _Pragma("unroll") \
        for (int t = 0; t < 8; ++t) \
            acc2[t] = __builtin_amdgcn_mfma_f32_16x16x32_bf16(a, b[t], acc2[t], 0, 0, 0); }

        G2ISSUE(0)
        G2ISSUE(1) G2BODY(0, 2)
        G2ISSUE(2) G2BODY(1, 2)
        G2ISSUE(3) G2BODY(2, 2)
        G2ISSUE(4) G2BODY(3, 2)
        G2ISSUE(5) G2BODY(4, 2)
        G2ISSUE(6) G2BODY(5, 2)
        G2ISSUE(7) G2BODY(6, 2)
                   G2BODY(7, 0)
#undef G2BODY
#undef G2ISSUE
    }
    __syncthreads();   // hT reads done; s_buf re-used for f32 out tile

    float* s_outf = reinterpret_cast<float*>(s_buf);
    {
        #pragma unroll
        for (int t = 0; t < 8; ++t)
            #pragma unroll
            for (int r = 0; r < 4; ++r)
                s_outf[(wave * 16 + quad * 4 + r) * OUT_LD + t * 16 + ln] = acc2[t][r];
    }
    __syncthreads();

    // Segment-reduce over sorted dest rows. Interior runs are sole-owner -> plain
    // store; boundary -> atomic.
    {
        const int c  = tid & 127;
        const int m0 = (tid >> 7) * 32;
        float run = 0.f;
        int cur = -1, rs = m0;
        for (int m = m0; m < m0 + 32; ++m) {
            int d = s_dest[m];
            float v = s_outf[m * OUT_LD + c];
            if (d != cur) {
                if (cur >= 0) {
                    float* p = &out[(size_t)cur * (2 * OUTD) + colbase + c];
                    if (rs > m0) *p = run; else atomicAdd(p, run);
                }
                cur = d; run = 0.f; rs = m;
            }
            if (d >= 0) run += v;
        }
        if (cur >= 0)
            atomicAdd(&out[(size_t)cur * (2 * OUTD) + colbase + c], run);
    }
}

extern "C" void kernel_launch(void* const* d_in, const int* in_sizes, int n_in,
                              void* d_out, int out_size, void* d_ws, size_t ws_size,
                              hipStream_t stream) {
    const float* x   = (const float*)d_in[0];
    const int*   ei  = (const int*)d_in[1];
    const float* ea  = (const float*)d_in[2];
    const float* W1o = (const float*)d_in[3];
    const float* b1o = (const float*)d_in[4];
    const float* W2o = (const float*)d_in[5];
    const float* b2o = (const float*)d_in[6];
    const float* W1i = (const float*)d_in[7];
    const float* b1i = (const float*)d_in[8];
    const float* W2i = (const float*)d_in[9];
    const float* b2i = (const float*)d_in[10];
    float* out = (float*)d_out;
    const int E = in_sizes[1] / 2;
    const int N = in_sizes[0] / DN;
    const int nch = (N + 1023) >> 10;          // chunks per branch (<=64 assumed)

    // workspace layout
    int* cnt      = (int*)d_ws;                // 2 (+pad to 16)
    int* chunkSum = cnt + 16;                  // 2*nch (<=128)
    int* hist     = chunkSum + 128;            // 2N
    int* cursor   = hist + 2 * (size_t)N;      // 2N
    int* list_out = cursor + 2 * (size_t)N;    // E
    int* list_in  = list_out + E;              // E
    unsigned short* W1po = (unsigned short*)(list_in + E);
    unsigned short* W1pi = W1po + DIN * HID;
    unsigned short* W2po = W1pi + DIN * HID;
    unsigned short* W2pi = W2po + HID * OUTD;
    unsigned short* xb   = W2pi + HID * OUTD;  // N*DN bf16

    // Defensive workspace bound (fail visibly, never fault).
    size_t need = (size_t)(144 + 4 * (size_t)N + 2 * (size_t)E) * 4
                + (size_t)(2 * DIN * HID + 2 * HID * OUTD) * 2
                + (size_t)N * DN * 2;
    if (need > ws_size) return;

    hipMemsetAsync(d_out, 0, (size_t)out_size * sizeof(float), stream);
    hipMemsetAsync(d_ws, 0, (576 + 8 * (size_t)N), stream);   // cnt+chunkSum+hist

    const int PACKN = 2 * DIN * HID + 2 * HID * OUTD;
    const int prepN = PACKN + E + N * DN / 8;
    prep_kernel<<<(prepN + 255) / 256, 256, 0, stream>>>(
        W1o, W1i, W2o, W2i, W1po, W1pi, W2po, W2pi, ei, E, N, hist, x, xb);

    scan1_kernel<<<2 * nch, 1024, 0, stream>>>(hist, cursor, chunkSum, N, nch);
    scan2_kernel<<<1, 128, 0, stream>>>(chunkSum, cnt, nch);
    reorder_kernel<<<(E + 255) / 256, 256, 0, stream>>>(
        ei, E, N, nch, cursor, chunkSum, list_out, list_in);

    const int nblk = (E + TE - 1) / TE + 2;    // device-side branch split via cnt[]
    mlp_scatter_kernel<<<nblk, NT, 0, stream>>>(
        xb, ei, ea, W1po, W1pi, b1o, b1i, W2po, W2pi, b2o, b2i,
        list_out, list_in, cnt, out, E);
}

// Round 8
// 608.807 us; speedup vs baseline: 1.0772x; 1.0772x over previous
//
#include <hip/hip_runtime.h>
#include <hip/hip_bf16.h>

typedef __attribute__((ext_vector_type(8))) short short8;
typedef __attribute__((ext_vector_type(8))) unsigned short ushort8;
typedef __attribute__((ext_vector_type(4))) float f32x4;
typedef __attribute__((ext_vector_type(2))) unsigned int uint2v;
typedef __attribute__((ext_vector_type(4))) unsigned int uint4v;

#define DN   128
#define DE   64
#define DIN  192
#define HID  256
#define OUTD 128
#define TE   64      // edges per block
#define NT   256     // threads per block (4 waves)
#define MSG_LD 200   // msg bf16 row stride (192 + 8 pad)
#define OUT_LD 132   // f32 out tile stride; 64*132*4 = 33792 = LDS union size
#define NMB  (TE / 16)

static __device__ __forceinline__ unsigned short f2b(float f) {
    unsigned int u = __float_as_uint(f);
    u += 0x7fffu + ((u >> 16) & 1u);
    return (unsigned short)(u >> 16);
}

// packed RNE f32x2 -> bf16x2 (gfx950 native)
static __device__ __forceinline__ unsigned int cvt_pk2(float lo, float hi) {
    unsigned int r;
    asm("v_cvt_pk_bf16_f32 %0, %1, %2" : "=v"(r) : "v"(lo), "v"(hi));
    return r;
}

// hardware transpose-read: per-lane addr selects an 8B slot in a 128B-aligned
// 4x16 bf16 row-major region; lane receives column (addr%128)/8 (elems col+j*16).
template<int OFF>
static __device__ __forceinline__ uint2v tr_read(unsigned addr) {
    uint2v d;
    asm volatile("ds_read_b64_tr_b16 %0, %1 offset:%c2"
                 : "=v"(d) : "v"(addr), "n"(OFF));
    return d;
}

// Fused prep: (a) pack 4 weight mats to bf16 fragment layout Wp[((k/32)*Nc+n)*32+(k%32)]
//     (coalesced WRITES, scattered reads -> L2 absorbs reads),
// (b) histogram dest rows per branch, (c) convert x to bf16.
__global__ __launch_bounds__(256)
void prep_kernel(const float* __restrict__ W1o, const float* __restrict__ W1i,
                 const float* __restrict__ W2o, const float* __restrict__ W2i,
                 unsigned short* __restrict__ W1po, unsigned short* __restrict__ W1pi,
                 unsigned short* __restrict__ W2po, unsigned short* __restrict__ W2pi,
                 const int* __restrict__ ei, int E, int N, int* __restrict__ hist,
                 const float* __restrict__ x, unsigned short* __restrict__ xb) {
    const int S1 = DIN * HID, S2v = HID * OUTD;
    const int PACKN = 2 * S1 + 2 * S2v;
    int idx = blockIdx.x * blockDim.x + threadIdx.x;
    if (idx < PACKN) {
        // j = PACKED index (linear per thread -> coalesced 2B stores).
        if (idx < 2 * S1) {
            const float* W = (idx < S1) ? W1o : W1i;
            unsigned short* Wp = (idx < S1) ? W1po : W1pi;
            int j = (idx < S1) ? idx : idx - S1;
            int k5 = j & 31, t = j >> 5;
            int n = t & (HID - 1), kq = t >> 8;
            Wp[j] = f2b(W[(kq * 32 + k5) * HID + n]);
        } else {
            const float* W = (idx < 2 * S1 + S2v) ? W2o : W2i;
            unsigned short* Wp = (idx < 2 * S1 + S2v) ? W2po : W2pi;
            int j = (idx < 2 * S1 + S2v) ? idx - 2 * S1 : idx - 2 * S1 - S2v;
            int k5 = j & 31, t = j >> 5;
            int n = t & (OUTD - 1), kq = t >> 7;
            Wp[j] = f2b(W[(kq * 32 + k5) * OUTD + n]);
        }
    } else if (idx < PACKN + E) {
        int e = idx - PACKN;
        int r = ei[e], c = ei[E + e];
        if      (r < c) atomicAdd(&hist[r], 1);
        else if (r > c) atomicAdd(&hist[N + r], 1);
    } else {
        int i = idx - PACKN - E;           // 8 x-floats per thread
        if (i < N * DN / 8) {
            float4 a = reinterpret_cast<const float4*>(x)[i * 2];
            float4 b = reinterpret_cast<const float4*>(x)[i * 2 + 1];
            ushort8 v = { f2b(a.x), f2b(a.y), f2b(a.z), f2b(a.w),
                          f2b(b.x), f2b(b.y), f2b(b.z), f2b(b.w) };
            reinterpret_cast<ushort8*>(xb)[i] = v;
        }
    }
}

// Fused scan: per-chunk exclusive scan of both branches' histograms, PLUS the
// finisher block (last to complete) scans the chunk totals and writes cnt[2].
// Cross-block chunkSum visibility via device-scope atomics (cross-XCD safe).
__global__ __launch_bounds__(1024)
void scan_kernel(const int* __restrict__ hist, int* __restrict__ cursor,
                 int* __restrict__ chunkSum, int* __restrict__ cnt,
                 int* __restrict__ done, int N, int nch) {
    __shared__ int s_ws[16];
    __shared__ int s_flag;
    const int br = blockIdx.x / nch, ch = blockIdx.x - br * nch;
    const int tid = threadIdx.x, lane = tid & 63, wv = tid >> 6;
    const int i = ch * 1024 + tid;
    int v = (i < N) ? hist[(size_t)br * N + i] : 0;
    int incl = v;
    #pragma unroll
    for (int d = 1; d < 64; d <<= 1) {
        int t = __shfl_up(incl, d, 64);
        if (lane >= d) incl += t;
    }
    if (lane == 63) s_ws[wv] = incl;
    __syncthreads();
    if (tid < 16) {
        int w = s_ws[tid];
        int wi = w;
        #pragma unroll
        for (int d = 1; d < 16; d <<= 1) {
            int t = __shfl_up(wi, d, 64);
            if (tid >= d) wi += t;
        }
        s_ws[tid] = wi - w;
    }
    __syncthreads();
    int excl = s_ws[wv] + incl - v;
    if (i < N) cursor[(size_t)br * N + i] = excl;
    if (tid == 1023)
        atomicExch(&chunkSum[br * nch + ch], excl + v);   // device-scope publish
    __threadfence();
    __syncthreads();
    if (tid == 0) {
        __threadfence();
        int old = atomicAdd(done, 1);
        s_flag = (old == (int)gridDim.x - 1) ? 1 : 0;
    }
    __syncthreads();
    if (s_flag && tid < 128) {       // finisher: scan chunk sums, write cnt
        const int fbr = tid >> 6, fl = tid & 63;
        int v2 = (fl < nch) ? atomicAdd(&chunkSum[fbr * nch + fl], 0) : 0;
        int inc2 = v2;
        #pragma unroll
        for (int d = 1; d < 64; d <<= 1) {
            int t = __shfl_up(inc2, d, 64);
            if (fl >= d) inc2 += t;
        }
        if (fl < nch) chunkSum[fbr * nch + fl] = inc2 - v2;
        if (fl == nch - 1) cnt[fbr] = inc2;
    }
}

// Scatter edges to sorted-by-dest-row positions.
__global__ __launch_bounds__(256)
void reorder_kernel(const int* __restrict__ ei, int E, int N, int nch,
                    int* __restrict__ cursor, const int* __restrict__ chunkSum,
                    int* __restrict__ list_out, int* __restrict__ list_in) {
    int e = blockIdx.x * blockDim.x + threadIdx.x;
    if (e >= E) return;
    int r = ei[e], c = ei[E + e];
    if (r == c) return;
    int br = (r < c) ? 0 : 1;
    int p = chunkSum[br * nch + (r >> 10)] + atomicAdd(&cursor[(size_t)br * N + r], 1);
    (br ? list_in : list_out)[p] = e;
}

__global__ __launch_bounds__(NT, 4)
void mlp_scatter_kernel(const unsigned short* __restrict__ xb,
                        const int* __restrict__ ei,
                        const float* __restrict__ ea,
                        const unsigned short* __restrict__ W1p_out,
                        const unsigned short* __restrict__ W1p_in,
                        const float* __restrict__ b1_out,
                        const float* __restrict__ b1_in,
                        const unsigned short* __restrict__ W2p_out,
                        const unsigned short* __restrict__ W2p_in,
                        const float* __restrict__ b2_out,
                        const float* __restrict__ b2_in,
                        const int* __restrict__ list_out,
                        const int* __restrict__ list_in,
                        const int* __restrict__ cnt,
                        float* __restrict__ out,
                        int E) {
    // s_buf union (33792 B): msg bf16 [64][MSG_LD] (25600B) -> hT blocked bf16
    //                        (32768B) -> out f32 [64][OUT_LD].
    __shared__ __align__(16) unsigned short s_buf[TE * 264];
    __shared__ int s_eid[TE], s_dest[TE], s_col[TE];

    // Device-side branch mapping: no empty half-grid.
    const int c0 = cnt[0], c1 = cnt[1];
    const int nb0 = (c0 + TE - 1) / TE;
    const int branch = (blockIdx.x >= nb0) ? 1 : 0;   // 0 = out-flow, 1 = in-flow
    const int lb = branch ? (blockIdx.x - nb0) : blockIdx.x;
    const int count = branch ? c1 : c0;
    if (lb * TE >= count) return;
    const int* list            = branch ? list_in : list_out;
    const unsigned short* W1p  = branch ? W1p_in  : W1p_out;
    const float* b1            = branch ? b1_in   : b1_out;
    const unsigned short* W2p  = branch ? W2p_in  : W2p_out;
    const float* b2            = branch ? b2_in   : b2_out;
    const int colbase          = branch ? 0 : OUTD;  // out = concat(flow_in, flow_out)

    const int tid = threadIdx.x;
    if (tid < TE) {
        int idx = lb * TE + tid;
        int e = (idx < count) ? list[idx] : -1;
        s_eid[tid]  = e;
        s_dest[tid] = (e >= 0) ? ei[e] : -1;       // sorted non-decreasing dest rows
        s_col[tid]  = (e >= 0) ? ei[E + e] : 0;
    }
    __syncthreads();

    // Gather msg = concat(xb[col] (bf16), cvt(edge_attr[e])) into LDS. 4 threads/edge.
    {
        const int le  = tid >> 2;
        const int sub = tid & 3;
        const int e   = s_eid[le];
        const ushort8* xrow = reinterpret_cast<const ushort8*>(xb) + (size_t)s_col[le] * (DN / 8);
        #pragma unroll
        for (int j = 0; j < 4; ++j) {
            int seg = sub + j * 4;                       // elems [seg*8, seg*8+8)
            ushort8 v = {0, 0, 0, 0, 0, 0, 0, 0};
            if (e >= 0) v = xrow[seg];
            *reinterpret_cast<ushort8*>(&s_buf[le * MSG_LD + seg * 8]) = v;
        }
        const float4* erow = reinterpret_cast<const float4*>(ea) + (size_t)e * (DE / 4);
        #pragma unroll
        for (int jj = 0; jj < 2; ++jj) {
            float4 v0 = make_float4(0.f, 0.f, 0.f, 0.f), v1 = v0;
            if (e >= 0) { v0 = erow[sub * 4 + jj * 2]; v1 = erow[sub * 4 + jj * 2 + 1]; }
            uint4v w = { cvt_pk2(v0.x, v0.y), cvt_pk2(v0.z, v0.w),
                         cvt_pk2(v1.x, v1.y), cvt_pk2(v1.z, v1.w) };
            *reinterpret_cast<uint4v*>(&s_buf[le * MSG_LD + DN + sub * 16 + jj * 8]) = w;
        }
    }
    __syncthreads();

    const int wave = tid >> 6;     // 0..3
    const int lane = tid & 63;
    const int ln   = lane & 15;
    const int quad = lane >> 4;

    // ---- GEMM1: h = relu(msg @ W1 + b1).  M=64 (4 m-frags), N=256 (64/wave), K=192.
    f32x4 acc[4][4];
    {
        const int nbase = wave * 64;
        float bias[4];
        #pragma unroll
        for (int t = 0; t < 4; ++t) bias[t] = b1[nbase + t * 16 + ln];
        #pragma unroll
        for (int mt = 0; mt < 4; ++mt)
            #pragma unroll
            for (int t = 0; t < 4; ++t)
                acc[mt][t] = (f32x4){bias[t], bias[t], bias[t], bias[t]};
        #pragma unroll
        for (int kt = 0; kt < DIN / 32; ++kt) {
            short8 a[4], b[4];
            #pragma unroll
            for (int mt = 0; mt < 4; ++mt)
                a[mt] = *reinterpret_cast<const short8*>(
                    &s_buf[(mt * 16 + ln) * MSG_LD + kt * 32 + quad * 8]);
            #pragma unroll
            for (int t = 0; t < 4; ++t)
                b[t] = *reinterpret_cast<const short8*>(
                    &W1p[((kt * HID + nbase + t * 16 + ln) << 5) + quad * 8]);
            #pragma unroll
            for (int mt = 0; mt < 4; ++mt)
                #pragma unroll
                for (int t = 0; t < 4; ++t)
                    acc[mt][t] = __builtin_amdgcn_mfma_f32_16x16x32_bf16(a[mt], b[t], acc[mt][t], 0, 0, 0);
        }
    }
    __syncthreads();   // msg reads done; s_buf re-used for blocked-transposed h

    // ReLU -> bf16 hT blocked: tile (nq=n/4, mb=m/16) holds 4x16 row-major bf16 at
    // elem ((nq*NMB + mb)*64 + (n&3)*16 + (m&15)). One cvt_pk pair + one b64 write.
    {
        const int nbase = wave * 64;
        #pragma unroll
        for (int mt = 0; mt < 4; ++mt)
            #pragma unroll
            for (int t = 0; t < 4; ++t) {
                int n = nbase + t * 16 + ln;
                float r0 = acc[mt][t][0], r1 = acc[mt][t][1];
                float r2 = acc[mt][t][2], r3 = acc[mt][t][3];
                r0 = r0 > 0.f ? r0 : 0.f;  r1 = r1 > 0.f ? r1 : 0.f;
                r2 = r2 > 0.f ? r2 : 0.f;  r3 = r3 > 0.f ? r3 : 0.f;
                unsigned int d0 = cvt_pk2(r0, r1);
                unsigned int d1 = cvt_pk2(r2, r3);
                int el = (((n >> 2) * NMB + mt) << 6) + ((n & 3) << 4) + (quad << 2);
                *reinterpret_cast<uint2v*>(&s_buf[el]) = (uint2v){d0, d1};
            }
    }
    __syncthreads();

    // ---- GEMM2: o = h @ W2 + b2.  M=64, N=128 (32/wave), K=256.  (R2-proven form)
    f32x4 acc2[4][2];
    {
        const int nb2 = wave * 32;
        float bz0 = b2[nb2 + ln];
        float bz1 = b2[nb2 + 16 + ln];
        #pragma unroll
        for (int mt = 0; mt < 4; ++mt) {
            acc2[mt][0] = (f32x4){bz0, bz0, bz0, bz0};
            acc2[mt][1] = (f32x4){bz1, bz1, bz1, bz1};
        }
        const unsigned trb = (unsigned)(uintptr_t)(&s_buf[quad * 512 + ln * 4]);
        short8 bn0 = *reinterpret_cast<const short8*>(&W2p[((nb2 + ln) << 5) + quad * 8]);
        short8 bn1 = *reinterpret_cast<const short8*>(&W2p[((nb2 + 16 + ln) << 5) + quad * 8]);

#define G2TR(kt, mt) { \
        uint2v t0 = tr_read<(kt) * 4096 + (mt) * 128>(trb); \
        uint2v t1 = tr_read<(kt) * 4096 + (mt) * 128 + 512>(trb); \
        a[mt] = __builtin_bit_cast(short8, (uint4v){t0.x, t0.y, t1.x, t1.y}); }

#define G2MM(mt) \
        acc2[mt][0] = __builtin_amdgcn_mfma_f32_16x16x32_bf16(a[mt], b0c, acc2[mt][0], 0, 0, 0); \
        acc2[mt][1] = __builtin_amdgcn_mfma_f32_16x16x32_bf16(a[mt], b1c, acc2[mt][1], 0, 0, 0);

#define G2STEP(kt) { \
        short8 a[4]; \
        G2TR(kt, 0) G2TR(kt, 1) G2TR(kt, 2) G2TR(kt, 3) \
        short8 b0c = bn0, b1c = bn1; \
        if ((kt) < 7) { \
            bn0 = *reinterpret_cast<const short8*>(&W2p[((((kt) + 1) * OUTD + nb2 + ln) << 5) + quad * 8]); \
            bn1 = *reinterpret_cast<const short8*>(&W2p[((((kt) + 1) * OUTD + nb2 + 16 + ln) << 5) + quad * 8]); \
        } \
        asm volatile("s_waitcnt lgkmcnt(0)"); \
        __builtin_amdgcn_sched_barrier(0); \
        G2MM(0) G2MM(1) G2MM(2) G2MM(3) }

        G2STEP(0) G2STEP(1) G2STEP(2) G2STEP(3)
        G2STEP(4) G2STEP(5) G2STEP(6) G2STEP(7)
#undef G2STEP
#undef G2MM
#undef G2TR
    }
    __syncthreads();   // hT reads done; s_buf re-used for f32 out tile

    float* s_outf = reinterpret_cast<float*>(s_buf);
    {
        const int nb2 = wave * 32;
        #pragma unroll
        for (int mt = 0; mt < 4; ++mt)
            #pragma unroll
            for (int t = 0; t < 2; ++t)
                #pragma unroll
                for (int r = 0; r < 4; ++r)
                    s_outf[(mt * 16 + quad * 4 + r) * OUT_LD + nb2 + t * 16 + ln] = acc2[mt][t][r];
    }
    __syncthreads();

    // Segment-reduce over sorted dest rows (float2: 2 cols/thread, 128 threads).
    // Interior runs sole-owner -> plain store; boundary -> atomic. Same run
    // boundaries as the b32 version (2 row-halves of 32).
    if (tid < 128) {
        const int c  = (tid & 63) * 2;
        const int m0 = (tid >> 6) * 32;
        float2 run = make_float2(0.f, 0.f);
        int cur = -1, rs = m0;
        for (int m = m0; m < m0 + 32; ++m) {
            int d = s_dest[m];
            float2 v = *reinterpret_cast<const float2*>(&s_outf[m * OUT_LD + c]);
            if (d != cur) {
                if (cur >= 0) {
                    float* p = &out[(size_t)cur * (2 * OUTD) + colbase + c];
                    if (rs > m0) *reinterpret_cast<float2*>(p) = run;
                    else { atomicAdd(p, run.x); atomicAdd(p + 1, run.y); }
                }
                cur = d; run = make_float2(0.f, 0.f); rs = m;
            }
            if (d >= 0) { run.x += v.x; run.y += v.y; }
        }
        if (cur >= 0) {
            float* p = &out[(size_t)cur * (2 * OUTD) + colbase + c];
            atomicAdd(p, run.x); atomicAdd(p + 1, run.y);
        }
    }
}

extern "C" void kernel_launch(void* const* d_in, const int* in_sizes, int n_in,
                              void* d_out, int out_size, void* d_ws, size_t ws_size,
                              hipStream_t stream) {
    const float* x   = (const float*)d_in[0];
    const int*   ei  = (const int*)d_in[1];
    const float* ea  = (const float*)d_in[2];
    const float* W1o = (const float*)d_in[3];
    const float* b1o = (const float*)d_in[4];
    const float* W2o = (const float*)d_in[5];
    const float* b2o = (const float*)d_in[6];
    const float* W1i = (const float*)d_in[7];
    const float* b1i = (const float*)d_in[8];
    const float* W2i = (const float*)d_in[9];
    const float* b2i = (const float*)d_in[10];
    float* out = (float*)d_out;
    const int E = in_sizes[1] / 2;
    const int N = in_sizes[0] / DN;
    const int nch = (N + 1023) >> 10;          // chunks per branch (<=64 assumed)

    // workspace layout
    int* cnt      = (int*)d_ws;                // cnt[0..1]; cnt[2] = done counter
    int* chunkSum = cnt + 16;                  // 2*nch (<=128)
    int* hist     = chunkSum + 128;            // 2N
    int* cursor   = hist + 2 * (size_t)N;      // 2N
    int* list_out = cursor + 2 * (size_t)N;    // E
    int* list_in  = list_out + E;              // E
    unsigned short* W1po = (unsigned short*)(list_in + E);
    unsigned short* W1pi = W1po + DIN * HID;
    unsigned short* W2po = W1pi + DIN * HID;
    unsigned short* W2pi = W2po + HID * OUTD;
    unsigned short* xb   = W2pi + HID * OUTD;  // N*DN bf16

    // Defensive workspace bound (fail visibly, never fault).
    size_t need = (size_t)(144 + 4 * (size_t)N + 2 * (size_t)E) * 4
                + (size_t)(2 * DIN * HID + 2 * HID * OUTD) * 2
                + (size_t)N * DN * 2;
    if (need > ws_size) return;

    hipMemsetAsync(d_out, 0, (size_t)out_size * sizeof(float), stream);
    hipMemsetAsync(d_ws, 0, (576 + 8 * (size_t)N), stream);   // cnt+done+chunkSum+hist

    const int PACKN = 2 * DIN * HID + 2 * HID * OUTD;
    const int prepN = PACKN + E + N * DN / 8;
    prep_kernel<<<(prepN + 255) / 256, 256, 0, stream>>>(
        W1o, W1i, W2o, W2i, W1po, W1pi, W2po, W2pi, ei, E, N, hist, x, xb);

    scan_kernel<<<2 * nch, 1024, 0, stream>>>(hist, cursor, chunkSum, cnt, cnt + 2, N, nch);
    reorder_kernel<<<(E + 255) / 256, 256, 0, stream>>>(
        ei, E, N, nch, cursor, chunkSum, list_out, list_in);

    const int nblk = (E + TE - 1) / TE + 2;    // device-side branch split via cnt[]
    mlp_scatter_kernel<<<nblk, NT, 0, stream>>>(
        xb, ei, ea, W1po, W1pi, b1o, b1i, W2po, W2pi, b2o, b2i,
        list_out, list_in, cnt, out, E);
}

// Round 9
// 583.867 us; speedup vs baseline: 1.1232x; 1.0427x over previous
//
#include <hip/hip_runtime.h>
#include <hip/hip_bf16.h>

typedef __attribute__((ext_vector_type(8))) short short8;
typedef __attribute__((ext_vector_type(8))) unsigned short ushort8;
typedef __attribute__((ext_vector_type(4))) float f32x4;
typedef __attribute__((ext_vector_type(2))) unsigned int uint2v;
typedef __attribute__((ext_vector_type(4))) unsigned int uint4v;

#define DN   128
#define DE   64
#define DIN  192
#define HID  256
#define OUTD 128
#define TE   64      // edges per block
#define NT   256     // threads per block (4 waves)
#define MSG_LD 200   // msg bf16 row stride (192 + 8 pad)
#define OUT_LD 132   // f32 out tile stride; 64*132*4 = 33792 = LDS union size
#define NMB  (TE / 16)
#define NXCD 8

static __device__ __forceinline__ unsigned short f2b(float f) {
    unsigned int u = __float_as_uint(f);
    u += 0x7fffu + ((u >> 16) & 1u);
    return (unsigned short)(u >> 16);
}

// packed RNE f32x2 -> bf16x2 (gfx950 native)
static __device__ __forceinline__ unsigned int cvt_pk2(float lo, float hi) {
    unsigned int r;
    asm("v_cvt_pk_bf16_f32 %0, %1, %2" : "=v"(r) : "v"(lo), "v"(hi));
    return r;
}

// hardware transpose-read: per-lane addr selects an 8B slot in a 128B-aligned
// 4x16 bf16 row-major region; lane receives column (addr%128)/8 (elems col+j*16).
template<int OFF>
static __device__ __forceinline__ uint2v tr_read(unsigned addr) {
    uint2v d;
    asm volatile("ds_read_b64_tr_b16 %0, %1 offset:%c2"
                 : "=v"(d) : "v"(addr), "n"(OFF));
    return d;
}

// Fused prep: (a) pack 4 weight mats to bf16 fragment layout Wp[((k/32)*Nc+n)*32+(k%32)],
// (b) histogram dest rows per branch, (c) convert x to bf16.   (R2-exact)
__global__ __launch_bounds__(256)
void prep_kernel(const float* __restrict__ W1o, const float* __restrict__ W1i,
                 const float* __restrict__ W2o, const float* __restrict__ W2i,
                 unsigned short* __restrict__ W1po, unsigned short* __restrict__ W1pi,
                 unsigned short* __restrict__ W2po, unsigned short* __restrict__ W2pi,
                 const int* __restrict__ ei, int E, int N, int* __restrict__ hist,
                 const float* __restrict__ x, unsigned short* __restrict__ xb) {
    const int S1 = DIN * HID, S2v = HID * OUTD;
    const int PACKN = 2 * S1 + 2 * S2v;
    int idx = blockIdx.x * blockDim.x + threadIdx.x;
    if (idx < PACKN) {
        const float* W; unsigned short* Wp; int Nc, j;
        if      (idx < S1)          { W = W1o; Wp = W1po; Nc = HID;  j = idx; }
        else if (idx < 2*S1)        { W = W1i; Wp = W1pi; Nc = HID;  j = idx - S1; }
        else if (idx < 2*S1 + S2v)  { W = W2o; Wp = W2po; Nc = OUTD; j = idx - 2*S1; }
        else                        { W = W2i; Wp = W2pi; Nc = OUTD; j = idx - 2*S1 - S2v; }
        int k = j / Nc, n = j - k * Nc;
        Wp[(((k >> 5) * Nc + n) << 5) + (k & 31)] = f2b(W[j]);
    } else if (idx < PACKN + E) {
        int e = idx - PACKN;
        int r = ei[e], c = ei[E + e];
        if      (r < c) atomicAdd(&hist[r], 1);
        else if (r > c) atomicAdd(&hist[N + r], 1);
    } else {
        int i = idx - PACKN - E;           // 8 x-floats per thread
        if (i < N * DN / 8) {
            float4 a = reinterpret_cast<const float4*>(x)[i * 2];
            float4 b = reinterpret_cast<const float4*>(x)[i * 2 + 1];
            ushort8 v = { f2b(a.x), f2b(a.y), f2b(a.z), f2b(a.w),
                          f2b(b.x), f2b(b.y), f2b(b.z), f2b(b.w) };
            reinterpret_cast<ushort8*>(xb)[i] = v;
        }
    }
}

// Per-chunk (1024 rows) exclusive scan of one branch's histogram.  (R2-exact)
__global__ __launch_bounds__(1024)
void scan1_kernel(const int* __restrict__ hist, int* __restrict__ cursor,
                  int* __restrict__ chunkSum, int N, int nch) {
    __shared__ int s_ws[16];
    const int br = blockIdx.x / nch, ch = blockIdx.x - br * nch;
    const int tid = threadIdx.x, lane = tid & 63, wv = tid >> 6;
    const int i = ch * 1024 + tid;
    int v = (i < N) ? hist[(size_t)br * N + i] : 0;
    int incl = v;
    #pragma unroll
    for (int d = 1; d < 64; d <<= 1) {
        int t = __shfl_up(incl, d, 64);
        if (lane >= d) incl += t;
    }
    if (lane == 63) s_ws[wv] = incl;
    __syncthreads();
    if (tid < 16) {
        int w = s_ws[tid];
        int wi = w;
        #pragma unroll
        for (int d = 1; d < 16; d <<= 1) {
            int t = __shfl_up(wi, d, 64);
            if (tid >= d) wi += t;
        }
        s_ws[tid] = wi - w;
    }
    __syncthreads();
    int excl = s_ws[wv] + incl - v;
    if (i < N) cursor[(size_t)br * N + i] = excl;
    if (tid == 1023) chunkSum[br * nch + ch] = excl + v;
}

// Scan chunk sums (nch <= 64 per branch).  (R2-exact)
__global__ __launch_bounds__(128)
void scan2_kernel(int* __restrict__ chunkSum, int* __restrict__ cnt, int nch) {
    const int br = threadIdx.x >> 6, lane = threadIdx.x & 63;
    int v = (lane < nch) ? chunkSum[br * nch + lane] : 0;
    int incl = v;
    #pragma unroll
    for (int d = 1; d < 64; d <<= 1) {
        int t = __shfl_up(incl, d, 64);
        if (lane >= d) incl += t;
    }
    if (lane < nch) chunkSum[br * nch + lane] = incl - v;
    if (lane == nch - 1) cnt[br] = incl;
}

// Scatter edges to sorted-by-dest-row positions.  (R2-exact)
__global__ __launch_bounds__(256)
void reorder_kernel(const int* __restrict__ ei, int E, int N, int nch,
                    int* __restrict__ cursor, const int* __restrict__ chunkSum,
                    int* __restrict__ list_out, int* __restrict__ list_in) {
    int e = blockIdx.x * blockDim.x + threadIdx.x;
    if (e >= E) return;
    int r = ei[e], c = ei[E + e];
    if (r == c) return;
    int br = (r < c) ? 0 : 1;
    int p = chunkSum[br * nch + (r >> 10)] + atomicAdd(&cursor[(size_t)br * N + r], 1);
    (br ? list_in : list_out)[p] = e;
}

__global__ __launch_bounds__(NT, 4)
void mlp_scatter_kernel(const unsigned short* __restrict__ xb,
                        const int* __restrict__ ei,
                        const float* __restrict__ ea,
                        const unsigned short* __restrict__ W1p_out,
                        const unsigned short* __restrict__ W1p_in,
                        const float* __restrict__ b1_out,
                        const float* __restrict__ b1_in,
                        const unsigned short* __restrict__ W2p_out,
                        const unsigned short* __restrict__ W2p_in,
                        const float* __restrict__ b2_out,
                        const float* __restrict__ b2_in,
                        const int* __restrict__ list_out,
                        const int* __restrict__ list_in,
                        const int* __restrict__ cnt,
                        float* __restrict__ out,
                        int E, int nblk) {
    // s_buf union (33792 B): msg bf16 [64][MSG_LD] -> hT blocked bf16 (32768B)
    //                        -> out f32 [64][OUT_LD].
    __shared__ __align__(16) unsigned short s_buf[TE * 264];
    __shared__ int s_eid[TE], s_dest[TE], s_col[TE];

    // XCD-aware bijective swizzle (T1, m204 formula): default dispatch round-robins
    // consecutive blocks over 8 XCD L2s, but consecutive blocks here write ADJACENT
    // sorted out-rows -> out-lines bounce between non-coherent L2s. Remap so each
    // XCD owns a contiguous block chunk.
    int bid;
    {
        const int orig = blockIdx.x;
        const int q = nblk / NXCD, r = nblk % NXCD;
        const int xcd = orig % NXCD, i = orig / NXCD;
        bid = (xcd < r ? xcd * (q + 1) : r * (q + 1) + (xcd - r) * q) + i;
    }

    // Device-side branch mapping: no empty half-grid.
    const int c0 = cnt[0], c1 = cnt[1];
    const int nb0 = (c0 + TE - 1) / TE;
    const int branch = (bid >= nb0) ? 1 : 0;   // 0 = out-flow, 1 = in-flow
    const int lb = branch ? (bid - nb0) : bid;
    const int count = branch ? c1 : c0;
    if (lb * TE >= count) return;
    const int* list            = branch ? list_in : list_out;
    const unsigned short* W1p  = branch ? W1p_in  : W1p_out;
    const float* b1            = branch ? b1_in   : b1_out;
    const unsigned short* W2p  = branch ? W2p_in  : W2p_out;
    const float* b2            = branch ? b2_in   : b2_out;
    const int colbase          = branch ? 0 : OUTD;  // out = concat(flow_in, flow_out)

    const int tid = threadIdx.x;
    if (tid < TE) {
        int idx = lb * TE + tid;
        int e = (idx < count) ? list[idx] : -1;
        s_eid[tid]  = e;
        s_dest[tid] = (e >= 0) ? ei[e] : -1;       // sorted non-decreasing dest rows
        s_col[tid]  = (e >= 0) ? ei[E + e] : 0;
    }
    __syncthreads();

    // Gather msg = concat(xb[col] (bf16), cvt(edge_attr[e])) into LDS. 4 threads/edge.
    {
        const int le  = tid >> 2;
        const int sub = tid & 3;
        const int e   = s_eid[le];
        const ushort8* xrow = reinterpret_cast<const ushort8*>(xb) + (size_t)s_col[le] * (DN / 8);
        #pragma unroll
        for (int j = 0; j < 4; ++j) {
            int seg = sub + j * 4;                       // elems [seg*8, seg*8+8)
            ushort8 v = {0, 0, 0, 0, 0, 0, 0, 0};
            if (e >= 0) v = xrow[seg];
            *reinterpret_cast<ushort8*>(&s_buf[le * MSG_LD + seg * 8]) = v;
        }
        const float4* erow = reinterpret_cast<const float4*>(ea) + (size_t)e * (DE / 4);
        #pragma unroll
        for (int j = 0; j < 4; ++j) {
            float4 v = make_float4(0.f, 0.f, 0.f, 0.f);
            if (e >= 0) v = erow[sub * 4 + j];
            unsigned int lo = cvt_pk2(v.x, v.y);
            unsigned int hi = cvt_pk2(v.z, v.w);
            *reinterpret_cast<uint2*>(&s_buf[le * MSG_LD + DN + sub * 16 + j * 4]) = make_uint2(lo, hi);
        }
    }
    __syncthreads();

    const int wave = tid >> 6;     // 0..3
    const int lane = tid & 63;
    const int ln   = lane & 15;
    const int quad = lane >> 4;

    // ---- GEMM1: h = relu(msg @ W1 + b1).  M=64 (4 m-frags), N=256 (64/wave), K=192.
    f32x4 acc[4][4];
    {
        const int nbase = wave * 64;
        float bias[4];
        #pragma unroll
        for (int t = 0; t < 4; ++t) bias[t] = b1[nbase + t * 16 + ln];
        #pragma unroll
        for (int mt = 0; mt < 4; ++mt)
            #pragma unroll
            for (int t = 0; t < 4; ++t)
                acc[mt][t] = (f32x4){bias[t], bias[t], bias[t], bias[t]};
        #pragma unroll
        for (int kt = 0; kt < DIN / 32; ++kt) {
            short8 a[4], b[4];
            #pragma unroll
            for (int mt = 0; mt < 4; ++mt)
                a[mt] = *reinterpret_cast<const short8*>(
                    &s_buf[(mt * 16 + ln) * MSG_LD + kt * 32 + quad * 8]);
            #pragma unroll
            for (int t = 0; t < 4; ++t)
                b[t] = *reinterpret_cast<const short8*>(
                    &W1p[((kt * HID + nbase + t * 16 + ln) << 5) + quad * 8]);
            #pragma unroll
            for (int mt = 0; mt < 4; ++mt)
                #pragma unroll
                for (int t = 0; t < 4; ++t)
                    acc[mt][t] = __builtin_amdgcn_mfma_f32_16x16x32_bf16(a[mt], b[t], acc[mt][t], 0, 0, 0);
        }
    }
    __syncthreads();   // msg reads done; s_buf re-used for blocked-transposed h

    // ReLU -> bf16 hT blocked: tile (nq=n/4, mb=m/16) holds 4x16 row-major bf16 at
    // elem ((nq*NMB + mb)*64 + (n&3)*16 + (m&15)). One cvt_pk pair + one b64 write.
    {
        const int nbase = wave * 64;
        #pragma unroll
        for (int mt = 0; mt < 4; ++mt)
            #pragma unroll
            for (int t = 0; t < 4; ++t) {
                int n = nbase + t * 16 + ln;
                float r0 = acc[mt][t][0], r1 = acc[mt][t][1];
                float r2 = acc[mt][t][2], r3 = acc[mt][t][3];
                r0 = r0 > 0.f ? r0 : 0.f;  r1 = r1 > 0.f ? r1 : 0.f;
                r2 = r2 > 0.f ? r2 : 0.f;  r3 = r3 > 0.f ? r3 : 0.f;
                unsigned int d0 = cvt_pk2(r0, r1);
                unsigned int d1 = cvt_pk2(r2, r3);
                int el = (((n >> 2) * NMB + mt) << 6) + ((n & 3) << 4) + (quad << 2);
                *reinterpret_cast<uint2v*>(&s_buf[el]) = (uint2v){d0, d1};
            }
    }
    __syncthreads();

    // ---- GEMM2: o = h @ W2 + b2.  M=64, N=128 (32/wave), K=256.  (R2-exact)
    f32x4 acc2[4][2];
    {
        const int nb2 = wave * 32;
        float bz0 = b2[nb2 + ln];
        float bz1 = b2[nb2 + 16 + ln];
        #pragma unroll
        for (int mt = 0; mt < 4; ++mt) {
            acc2[mt][0] = (f32x4){bz0, bz0, bz0, bz0};
            acc2[mt][1] = (f32x4){bz1, bz1, bz1, bz1};
        }
        const unsigned trb = (unsigned)(uintptr_t)(&s_buf[quad * 512 + ln * 4]);
        short8 bn0 = *reinterpret_cast<const short8*>(&W2p[((nb2 + ln) << 5) + quad * 8]);
        short8 bn1 = *reinterpret_cast<const short8*>(&W2p[((nb2 + 16 + ln) << 5) + quad * 8]);

#define G2TR(kt, mt) { \
        uint2v t0 = tr_read<(kt) * 4096 + (mt) * 128>(trb); \
        uint2v t1 = tr_read<(kt) * 4096 + (mt) * 128 + 512>(trb); \
        a[mt] = __builtin_bit_cast(short8, (uint4v){t0.x, t0.y, t1.x, t1.y}); }

#define G2MM(mt) \
        acc2[mt][0] = __builtin_amdgcn_mfma_f32_16x16x32_bf16(a[mt], b0c, acc2[mt][0], 0, 0, 0); \
        acc2[mt][1] = __builtin_amdgcn_mfma_f32_16x16x32_bf16(a[mt], b1c, acc2[mt][1], 0, 0, 0);

#define G2STEP(kt) { \
        short8 a[4]; \
        G2TR(kt, 0) G2TR(kt, 1) G2TR(kt, 2) G2TR(kt, 3) \
        short8 b0c = bn0, b1c = bn1; \
        if ((kt) < 7) { \
            bn0 = *reinterpret_cast<const short8*>(&W2p[((((kt) + 1) * OUTD + nb2 + ln) << 5) + quad * 8]); \
            bn1 = *reinterpret_cast<const short8*>(&W2p[((((kt) + 1) * OUTD + nb2 + 16 + ln) << 5) + quad * 8]); \
        } \
        asm volatile("s_waitcnt lgkmcnt(0)"); \
        __builtin_amdgcn_sched_barrier(0); \
        G2MM(0) G2MM(1) G2MM(2) G2MM(3) }

        G2STEP(0) G2STEP(1) G2STEP(2) G2STEP(3)
        G2STEP(4) G2STEP(5) G2STEP(6) G2STEP(7)
#undef G2STEP
#undef G2MM
#undef G2TR
    }
    __syncthreads();   // hT reads done; s_buf re-used for f32 out tile

    float* s_outf = reinterpret_cast<float*>(s_buf);
    {
        const int nb2 = wave * 32;
        #pragma unroll
        for (int mt = 0; mt < 4; ++mt)
            #pragma unroll
            for (int t = 0; t < 2; ++t)
                #pragma unroll
                for (int r = 0; r < 4; ++r)
                    s_outf[(mt * 16 + quad * 4 + r) * OUT_LD + nb2 + t * 16 + ln] = acc2[mt][t][r];
    }
    __syncthreads();

    // Segment-reduce over sorted dest rows.  (R2-exact b32 epilogue)
    {
        const int c  = tid & 127;
        const int m0 = (tid >> 7) * 32;
        float run = 0.f;
        int cur = -1, rs = m0;
        for (int m = m0; m < m0 + 32; ++m) {
            int d = s_dest[m];
            float v = s_outf[m * OUT_LD + c];
            if (d != cur) {
                if (cur >= 0) {
                    float* p = &out[(size_t)cur * (2 * OUTD) + colbase + c];
                    if (rs > m0) *p = run; else atomicAdd(p, run);
                }
                cur = d; run = 0.f; rs = m;
            }
            if (d >= 0) run += v;
        }
        if (cur >= 0)
            atomicAdd(&out[(size_t)cur * (2 * OUTD) + colbase + c], run);
    }
}

extern "C" void kernel_launch(void* const* d_in, const int* in_sizes, int n_in,
                              void* d_out, int out_size, void* d_ws, size_t ws_size,
                              hipStream_t stream) {
    const float* x   = (const float*)d_in[0];
    const int*   ei  = (const int*)d_in[1];
    const float* ea  = (const float*)d_in[2];
    const float* W1o = (const float*)d_in[3];
    const float* b1o = (const float*)d_in[4];
    const float* W2o = (const float*)d_in[5];
    const float* b2o = (const float*)d_in[6];
    const float* W1i = (const float*)d_in[7];
    const float* b1i = (const float*)d_in[8];
    const float* W2i = (const float*)d_in[9];
    const float* b2i = (const float*)d_in[10];
    float* out = (float*)d_out;
    const int E = in_sizes[1] / 2;
    const int N = in_sizes[0] / DN;
    const int nch = (N + 1023) >> 10;          // chunks per branch (<=64 assumed)

    // workspace layout
    int* cnt      = (int*)d_ws;                // 2 (+pad to 16)
    int* chunkSum = cnt + 16;                  // 2*nch (<=128)
    int* hist     = chunkSum + 128;            // 2N
    int* cursor   = hist + 2 * (size_t)N;      // 2N
    int* list_out = cursor + 2 * (size_t)N;    // E
    int* list_in  = list_out + E;              // E
    unsigned short* W1po = (unsigned short*)(list_in + E);
    unsigned short* W1pi = W1po + DIN * HID;
    unsigned short* W2po = W1pi + DIN * HID;
    unsigned short* W2pi = W2po + HID * OUTD;
    unsigned short* xb   = W2pi + HID * OUTD;  // N*DN bf16

    // Defensive workspace bound (fail visibly, never fault).
    size_t need = (size_t)(144 + 4 * (size_t)N + 2 * (size_t)E) * 4
                + (size_t)(2 * DIN * HID + 2 * HID * OUTD) * 2
                + (size_t)N * DN * 2;
    if (need > ws_size) return;

    hipMemsetAsync(d_out, 0, (size_t)out_size * sizeof(float), stream);
    hipMemsetAsync(d_ws, 0, (576 + 8 * (size_t)N), stream);   // cnt+chunkSum+hist

    const int PACKN = 2 * DIN * HID + 2 * HID * OUTD;
    const int prepN = PACKN + E + N * DN / 8;
    prep_kernel<<<(prepN + 255) / 256, 256, 0, stream>>>(
        W1o, W1i, W2o, W2i, W1po, W1pi, W2po, W2pi, ei, E, N, hist, x, xb);

    scan1_kernel<<<2 * nch, 1024, 0, stream>>>(hist, cursor, chunkSum, N, nch);
    scan2_kernel<<<1, 128, 0, stream>>>(chunkSum, cnt, nch);
    reorder_kernel<<<(E + 255) / 256, 256, 0, stream>>>(
        ei, E, N, nch, cursor, chunkSum, list_out, list_in);

    const int nblk = (E + TE - 1) / TE + 2;    // device-side branch split via cnt[]
    mlp_scatter_kernel<<<nblk, NT, 0, stream>>>(
        xb, ei, ea, W1po, W1pi, b1o, b1i, W2po, W2pi, b2o, b2i,
        list_out, list_in, cnt, out, E, nblk);
}